// Round 1
// baseline (1191.396 us; speedup 1.0000x reference)
//
#include <hip/hip_runtime.h>

#define BN 4
#define H 352
#define W 1216
#define NUMCH 8
#define PROP_TIME 18

constexpr int HW  = H * W;        // 428032
constexpr int PIX = BN * HW;      // 1712128
constexpr int NBLK = (PIX + 255) / 256;

__device__ __forceinline__ float bilin(const float* __restrict__ plane, float ys, float xs) {
    float y0f = floorf(ys), x0f = floorf(xs);
    float wy = ys - y0f, wx = xs - x0f;
    int y0 = (int)y0f, x0 = (int)x0f;
    int y1 = y0 + 1, x1 = x0 + 1;
    bool yv0 = (y0 >= 0) & (y0 < H);
    bool yv1 = (y1 >= 0) & (y1 < H);
    bool xv0 = (x0 >= 0) & (x0 < W);
    bool xv1 = (x1 >= 0) & (x1 < W);
    int yc0 = min(max(y0, 0), H - 1), yc1 = min(max(y1, 0), H - 1);
    int xc0 = min(max(x0, 0), W - 1), xc1 = min(max(x1, 0), W - 1);
    float v00 = (yv0 && xv0) ? plane[yc0 * W + xc0] : 0.f;
    float v01 = (yv0 && xv1) ? plane[yc0 * W + xc1] : 0.f;
    float v10 = (yv1 && xv0) ? plane[yc1 * W + xc0] : 0.f;
    float v11 = (yv1 && xv1) ? plane[yc1 * W + xc1] : 0.f;
    return (1.f - wy) * ((1.f - wx) * v00 + wx * v01) + wy * ((1.f - wx) * v10 + wx * v11);
}

__global__ __launch_bounds__(256) void prep_kernel(
    const float* __restrict__ guidance, const float* __restrict__ confidence,
    const float* __restrict__ W_oa, const float* __restrict__ b_oa,
    const float* __restrict__ aff_scale,
    float* __restrict__ out_offset, float* __restrict__ out_aff)
{
    __shared__ float w_s[24 * 72];
    __shared__ float b_s[24];
    for (int i = threadIdx.x; i < 24 * 72; i += 256) w_s[i] = W_oa[i];
    if (threadIdx.x < 24) b_s[threadIdx.x] = b_oa[threadIdx.x];
    __syncthreads();

    int idx = blockIdx.x * 256 + threadIdx.x;
    if (idx >= PIX) return;
    int x = idx % W;
    int t = idx / W;
    int y = t % H;
    int b = t / H;

    const float* gbase = guidance + (size_t)b * NUMCH * HW;
    float acc[24];
    #pragma unroll
    for (int o = 0; o < 24; o++) acc[o] = b_s[o];

    for (int i = 0; i < NUMCH; i++) {
        #pragma unroll
        for (int dy = -1; dy <= 1; dy++) {
            int yy = y + dy;
            bool yok = (yy >= 0) && (yy < H);
            #pragma unroll
            for (int dx = -1; dx <= 1; dx++) {
                int xx = x + dx;
                float g = (yok && xx >= 0 && xx < W) ? gbase[i * HW + yy * W + xx] : 0.f;
                int wi = i * 9 + (dy + 1) * 3 + (dx + 1);
                #pragma unroll
                for (int o = 0; o < 24; o++) acc[o] = fmaf(g, w_s[o * 72 + wi], acc[o]);
            }
        }
    }

    // offsets: post-insertion neighbor n -> (off_y, off_x)
    float offy[9], offx[9];
    #pragma unroll
    for (int n = 0; n < 9; n++) {
        if (n < 4)      { offy[n] = acc[2 * n];     offx[n] = acc[2 * n + 1]; }
        else if (n == 4){ offy[n] = 0.f;            offx[n] = 0.f; }
        else            { offy[n] = acc[2 * n - 2]; offx[n] = acc[2 * n - 1]; }
    }

    size_t obase = (size_t)b * 18 * HW + (size_t)y * W + x;
    #pragma unroll
    for (int n = 0; n < 9; n++) {
        out_offset[obase + (size_t)(2 * n) * HW]     = offy[n];
        out_offset[obase + (size_t)(2 * n + 1) * HW] = offx[n];
    }

    float scale = aff_scale[0] + 1e-8f;
    const float* conf = confidence + (size_t)b * HW;
    float aff[8];
    float s = 0.f;
    #pragma unroll
    for (int i = 0; i < 8; i++) {
        int n = (i < 4) ? i : i + 1;
        float a = tanhf(acc[16 + i]) / scale;
        float c = bilin(conf, (float)y + offy[n], (float)x + offx[n]);
        a *= c;
        aff[i] = a;
        s += fabsf(a);
    }
    float denom = fmaxf(s + 1e-4f, 1.0f);
    float sum = 0.f;
    #pragma unroll
    for (int i = 0; i < 8; i++) { aff[i] /= denom; sum += aff[i]; }
    float aref = 1.f - sum;

    size_t abase = (size_t)b * 9 * HW + (size_t)y * W + x;
    #pragma unroll
    for (int n = 0; n < 9; n++) {
        float v = (n < 4) ? aff[n] : ((n == 4) ? aref : aff[n - 1]);
        out_aff[abase + (size_t)n * HW] = v;
    }
}

__global__ __launch_bounds__(256) void prop_kernel(
    const float* __restrict__ src, float* __restrict__ dst,
    const float* __restrict__ out_offset, const float* __restrict__ out_aff)
{
    int idx = blockIdx.x * 256 + threadIdx.x;
    if (idx >= PIX) return;
    int x = idx % W;
    int t = idx / W;
    int y = t % H;
    int b = t / H;

    const float* plane = src + (size_t)b * HW;
    size_t obase = (size_t)b * 18 * HW + (size_t)y * W + x;
    size_t abase = (size_t)b * 9 * HW + (size_t)y * W + x;

    float r = 0.f;
    #pragma unroll
    for (int n = 0; n < 9; n++) {
        float offy = out_offset[obase + (size_t)(2 * n) * HW];
        float offx = out_offset[obase + (size_t)(2 * n + 1) * HW];
        float a    = out_aff[abase + (size_t)n * HW];
        float ys = (float)y + (float)(n / 3 - 1) + offy;
        float xs = (float)x + (float)(n % 3 - 1) + offx;
        r = fmaf(a, bilin(plane, ys, xs), r);
    }
    dst[(size_t)b * HW + (size_t)y * W + x] = r;
}

extern "C" void kernel_launch(void* const* d_in, const int* in_sizes, int n_in,
                              void* d_out, int out_size, void* d_ws, size_t ws_size,
                              hipStream_t stream) {
    const float* guidance   = (const float*)d_in[0];
    const float* confidence = (const float*)d_in[1];
    const float* feat_init  = (const float*)d_in[2];
    const float* W_oa       = (const float*)d_in[3];
    const float* b_oa       = (const float*)d_in[4];
    const float* aff_scale  = (const float*)d_in[5];

    float* out        = (float*)d_out;
    float* out_feat   = out;                                   // B*HW
    float* out_offset = out + (size_t)PIX;                     // B*18*HW
    float* out_aff    = out + (size_t)PIX + (size_t)BN * 18 * HW; // B*9*HW

    float* ws0 = (float*)d_ws;                                 // B*HW floats

    prep_kernel<<<NBLK, 256, 0, stream>>>(guidance, confidence, W_oa, b_oa,
                                          aff_scale, out_offset, out_aff);

    const float* src = feat_init;
    for (int k = 1; k <= PROP_TIME; k++) {
        float* dst = (k % 2 == 1) ? ws0 : out_feat;   // iter 18 (even) lands in d_out
        prop_kernel<<<NBLK, 256, 0, stream>>>(src, dst, out_offset, out_aff);
        src = dst;
    }
}

// Round 2
// 1100.657 us; speedup vs baseline: 1.0824x; 1.0824x over previous
//
#include <hip/hip_runtime.h>
#include <hip/hip_fp16.h>

#define BN 4
#define H 352
#define W 1216
#define NUMCH 8
#define PROP_TIME 18

constexpr int HW  = H * W;        // 428032
constexpr int PIX = BN * HW;      // 1712128
constexpr int NBLK = (PIX + 255) / 256;

__device__ __forceinline__ float bilin(const float* __restrict__ plane, float ys, float xs) {
    float y0f = floorf(ys), x0f = floorf(xs);
    float wy = ys - y0f, wx = xs - x0f;
    int y0 = (int)y0f, x0 = (int)x0f;
    int y1 = y0 + 1, x1 = x0 + 1;
    bool yv0 = (y0 >= 0) & (y0 < H);
    bool yv1 = (y1 >= 0) & (y1 < H);
    bool xv0 = (x0 >= 0) & (x0 < W);
    bool xv1 = (x1 >= 0) & (x1 < W);
    int yc0 = min(max(y0, 0), H - 1), yc1 = min(max(y1, 0), H - 1);
    int xc0 = min(max(x0, 0), W - 1), xc1 = min(max(x1, 0), W - 1);
    float v00 = (yv0 && xv0) ? plane[yc0 * W + xc0] : 0.f;
    float v01 = (yv0 && xv1) ? plane[yc0 * W + xc1] : 0.f;
    float v10 = (yv1 && xv0) ? plane[yc1 * W + xc0] : 0.f;
    float v11 = (yv1 && xv1) ? plane[yc1 * W + xc1] : 0.f;
    return (1.f - wy) * ((1.f - wx) * v00 + wx * v01) + wy * ((1.f - wx) * v10 + wx * v11);
}

// Prep: direct-SGPR weights (uniform global loads), guidance taps in VGPRs.
__global__ __launch_bounds__(256) void prep_kernel(
    const float* __restrict__ guidance, const float* __restrict__ confidence,
    const float* __restrict__ W_oa, const float* __restrict__ b_oa,
    const float* __restrict__ aff_scale,
    float* __restrict__ out_offset, float* __restrict__ out_aff,
    unsigned int* __restrict__ p_offyx, unsigned short* __restrict__ p_aff)
{
    int idx = blockIdx.x * 256 + threadIdx.x;
    if (idx >= PIX) return;
    int x = idx % W;
    int t = idx / W;
    int y = t % H;
    int b = t / H;

    const float* gbase = guidance + (size_t)b * NUMCH * HW;
    float g[72];
    #pragma unroll
    for (int i = 0; i < NUMCH; i++) {
        #pragma unroll
        for (int dy = -1; dy <= 1; dy++) {
            int yy = y + dy;
            bool yok = (yy >= 0) && (yy < H);
            const float* row = gbase + i * HW + yy * W;
            #pragma unroll
            for (int dx = -1; dx <= 1; dx++) {
                int xx = x + dx;
                g[i * 9 + (dy + 1) * 3 + (dx + 1)] =
                    (yok && xx >= 0 && xx < W) ? row[xx] : 0.f;
            }
        }
    }

    float acc[24];
    #pragma unroll
    for (int o = 0; o < 24; o++) {
        float a = b_oa[o];                      // uniform -> SGPR
        #pragma unroll
        for (int k = 0; k < 72; k++)
            a = fmaf(g[k], W_oa[o * 72 + k], a); // uniform contiguous -> s_load_dwordx16
        acc[o] = a;
    }

    float offy[9], offx[9];
    #pragma unroll
    for (int n = 0; n < 9; n++) {
        if (n < 4)       { offy[n] = acc[2 * n];     offx[n] = acc[2 * n + 1]; }
        else if (n == 4) { offy[n] = 0.f;            offx[n] = 0.f; }
        else             { offy[n] = acc[2 * n - 2]; offx[n] = acc[2 * n - 1]; }
    }

    size_t obase = (size_t)b * 18 * HW + (size_t)y * W + x;
    #pragma unroll
    for (int n = 0; n < 9; n++) {
        out_offset[obase + (size_t)(2 * n) * HW]     = offy[n];
        out_offset[obase + (size_t)(2 * n + 1) * HW] = offx[n];
    }

    float scale = aff_scale[0] + 1e-8f;
    const float* conf = confidence + (size_t)b * HW;
    float aff[8];
    float s = 0.f;
    #pragma unroll
    for (int i = 0; i < 8; i++) {
        int n = (i < 4) ? i : i + 1;
        float a = tanhf(acc[16 + i]) / scale;
        float c = bilin(conf, (float)y + offy[n], (float)x + offx[n]);
        a *= c;
        aff[i] = a;
        s += fabsf(a);
    }
    float denom = fmaxf(s + 1e-4f, 1.0f);
    float sum = 0.f;
    #pragma unroll
    for (int i = 0; i < 8; i++) { aff[i] /= denom; sum += aff[i]; }
    float aref = 1.f - sum;

    float aff9[9];
    #pragma unroll
    for (int n = 0; n < 9; n++)
        aff9[n] = (n < 4) ? aff[n] : ((n == 4) ? aref : aff[n - 1]);

    size_t abase = (size_t)b * 9 * HW + (size_t)y * W + x;
    #pragma unroll
    for (int n = 0; n < 9; n++)
        out_aff[abase + (size_t)n * HW] = aff9[n];

    if (p_offyx) {   // fast path: fp16 param planes for propagation
        #pragma unroll
        for (int m = 0; m < 8; m++) {
            int n = (m < 4) ? m : m + 1;
            unsigned int lo = __half_as_ushort(__float2half_rn(offy[n]));
            unsigned int hi = __half_as_ushort(__float2half_rn(offx[n]));
            p_offyx[(size_t)m * PIX + idx] = lo | (hi << 16);
        }
        #pragma unroll
        for (int n = 0; n < 9; n++)
            p_aff[(size_t)n * PIX + idx] = __half_as_ushort(__float2half_rn(aff9[n]));
    }
}

// Fast propagation: fp16 params, center neighbor special-cased.
__global__ __launch_bounds__(256) void prop_fast(
    const float* __restrict__ src, float* __restrict__ dst,
    const unsigned int* __restrict__ p_offyx, const unsigned short* __restrict__ p_aff)
{
    int idx = blockIdx.x * 256 + threadIdx.x;
    if (idx >= PIX) return;
    int x = idx % W;
    int t = idx / W;
    int y = t % H;
    int b = t / H;
    const float* plane = src + (size_t)b * HW;
    int pix = y * W + x;

    float r = __half2float(__ushort_as_half(p_aff[(size_t)4 * PIX + idx])) * plane[pix];
    #pragma unroll
    for (int m = 0; m < 8; m++) {
        int n = (m < 4) ? m : m + 1;
        unsigned int p = p_offyx[(size_t)m * PIX + idx];
        float offy = __half2float(__ushort_as_half((unsigned short)(p & 0xffffu)));
        float offx = __half2float(__ushort_as_half((unsigned short)(p >> 16)));
        float a    = __half2float(__ushort_as_half(p_aff[(size_t)n * PIX + idx]));
        float ys = (float)(y + n / 3 - 1) + offy;
        float xs = (float)(x + n % 3 - 1) + offx;
        r = fmaf(a, bilin(plane, ys, xs), r);
    }
    dst[idx] = r;
}

// Fallback propagation (f32 params from d_out) if ws too small.
__global__ __launch_bounds__(256) void prop_slow(
    const float* __restrict__ src, float* __restrict__ dst,
    const float* __restrict__ out_offset, const float* __restrict__ out_aff)
{
    int idx = blockIdx.x * 256 + threadIdx.x;
    if (idx >= PIX) return;
    int x = idx % W;
    int t = idx / W;
    int y = t % H;
    int b = t / H;

    const float* plane = src + (size_t)b * HW;
    size_t obase = (size_t)b * 18 * HW + (size_t)y * W + x;
    size_t abase = (size_t)b * 9 * HW + (size_t)y * W + x;

    float r = 0.f;
    #pragma unroll
    for (int n = 0; n < 9; n++) {
        float offy = out_offset[obase + (size_t)(2 * n) * HW];
        float offx = out_offset[obase + (size_t)(2 * n + 1) * HW];
        float a    = out_aff[abase + (size_t)n * HW];
        float ys = (float)y + (float)(n / 3 - 1) + offy;
        float xs = (float)x + (float)(n % 3 - 1) + offx;
        r = fmaf(a, bilin(plane, ys, xs), r);
    }
    dst[(size_t)b * HW + (size_t)y * W + x] = r;
}

extern "C" void kernel_launch(void* const* d_in, const int* in_sizes, int n_in,
                              void* d_out, int out_size, void* d_ws, size_t ws_size,
                              hipStream_t stream) {
    const float* guidance   = (const float*)d_in[0];
    const float* confidence = (const float*)d_in[1];
    const float* feat_init  = (const float*)d_in[2];
    const float* W_oa       = (const float*)d_in[3];
    const float* b_oa       = (const float*)d_in[4];
    const float* aff_scale  = (const float*)d_in[5];

    float* out        = (float*)d_out;
    float* out_feat   = out;                                      // B*HW
    float* out_offset = out + (size_t)PIX;                        // B*18*HW
    float* out_aff    = out + (size_t)PIX + (size_t)BN * 18 * HW; // B*9*HW

    float* ws_f = (float*)d_ws;
    // fast-path ws layout: featA | featB | offyx(8 planes u32) | aff(9 planes u16)
    size_t need = (size_t)PIX * 4 * 2 + (size_t)PIX * 4 * 8 + (size_t)PIX * 2 * 9;
    bool fast = (ws_size >= need);

    float*          featA   = ws_f;
    float*          featB   = ws_f + (size_t)PIX;
    unsigned int*   p_offyx = (unsigned int*)(ws_f + (size_t)2 * PIX);
    unsigned short* p_aff   = (unsigned short*)(ws_f + (size_t)2 * PIX + (size_t)8 * PIX);

    prep_kernel<<<NBLK, 256, 0, stream>>>(guidance, confidence, W_oa, b_oa, aff_scale,
                                          out_offset, out_aff,
                                          fast ? p_offyx : nullptr,
                                          fast ? p_aff : nullptr);

    const float* src = feat_init;
    if (fast) {
        for (int k = 1; k <= PROP_TIME; k++) {
            float* dst = (k == PROP_TIME) ? out_feat : ((k & 1) ? featA : featB);
            prop_fast<<<NBLK, 256, 0, stream>>>(src, dst, p_offyx, p_aff);
            src = dst;
        }
    } else {
        for (int k = 1; k <= PROP_TIME; k++) {
            float* dst = (k % 2 == 1) ? ws_f : out_feat;
            prop_slow<<<NBLK, 256, 0, stream>>>(src, dst, out_offset, out_aff);
            src = dst;
        }
    }
}

// Round 3
// 736.127 us; speedup vs baseline: 1.6185x; 1.4952x over previous
//
#include <hip/hip_runtime.h>
#include <hip/hip_fp16.h>

#define BN 4
#define H 352
#define W 1216
#define NUMCH 8
#define PROP_TIME 18

constexpr int HW  = H * W;        // 428032
constexpr int PIX = BN * HW;      // 1712128 (divisible by 256)

// prop tiling
#define XB 64
#define YB 4
#define TR (YB + 4)               // 8 tile rows
#define TC (XB + 6)               // 70 tile cols
#define TS 72                     // padded LDS row stride (floats)
constexpr int NXB = W / XB;       // 19
constexpr int NYB = H / YB;       // 88

__device__ __forceinline__ float bilin(const float* __restrict__ plane, float ys, float xs) {
    float y0f = floorf(ys), x0f = floorf(xs);
    float wy = ys - y0f, wx = xs - x0f;
    int y0 = (int)y0f, x0 = (int)x0f;
    int y1 = y0 + 1, x1 = x0 + 1;
    bool yv0 = (y0 >= 0) & (y0 < H);
    bool yv1 = (y1 >= 0) & (y1 < H);
    bool xv0 = (x0 >= 0) & (x0 < W);
    bool xv1 = (x1 >= 0) & (x1 < W);
    int yc0 = min(max(y0, 0), H - 1), yc1 = min(max(y1, 0), H - 1);
    int xc0 = min(max(x0, 0), W - 1), xc1 = min(max(x1, 0), W - 1);
    float v00 = (yv0 && xv0) ? plane[yc0 * W + xc0] : 0.f;
    float v01 = (yv0 && xv1) ? plane[yc0 * W + xc1] : 0.f;
    float v10 = (yv1 && xv0) ? plane[yc1 * W + xc0] : 0.f;
    float v11 = (yv1 && xv1) ? plane[yc1 * W + xc1] : 0.f;
    return (1.f - wy) * ((1.f - wx) * v00 + wx * v01) + wy * ((1.f - wx) * v10 + wx * v11);
}

__device__ __forceinline__ float tanh_fast(float v) {
    float e = __expf(fminf(fmaxf(2.f * v, -20.f), 20.f));
    return (e - 1.f) / (e + 1.f);
}

__device__ __forceinline__ unsigned pk2(float lo, float hi) {
    return (unsigned)__half_as_ushort(__float2half_rn(lo)) |
           ((unsigned)__half_as_ushort(__float2half_rn(hi)) << 16);
}
__device__ __forceinline__ float uph_lo(unsigned p) {
    return __half2float(__ushort_as_half((unsigned short)(p & 0xffffu)));
}
__device__ __forceinline__ float uph_hi(unsigned p) {
    return __half2float(__ushort_as_half((unsigned short)(p >> 16)));
}

// Transpose W_oa (24,72) -> Wt (72,24) so conv inner loop reads 24 contiguous
// uniform floats per (channel,tap) -> s_load.
__global__ void transpose_w(const float* __restrict__ W_oa, float* __restrict__ Wt) {
    int j = blockIdx.x * 256 + threadIdx.x;
    if (j < 24 * 72) {
        int o = j / 72, r = j % 72;
        Wt[r * 24 + o] = W_oa[j];
    }
}

// NOTE: no early-return; grid is exact (PIX % 256 == 0) so uniform weight
// loads are not control-dependent on a divergent branch -> scalarizable.
__global__ __launch_bounds__(256) void prep_kernel(
    const float* __restrict__ guidance, const float* __restrict__ confidence,
    const float* __restrict__ Wt, const float* __restrict__ b_oa,
    const float* __restrict__ aff_scale,
    float* __restrict__ out_offset, float* __restrict__ out_aff,
    uint4* __restrict__ p_o03, uint4* __restrict__ p_o47,
    uint4* __restrict__ p_ap, float* __restrict__ p_a4)
{
    int idx = blockIdx.x * 256 + threadIdx.x;
    int x = idx % W;
    int t = idx / W;
    int y = t % H;
    int b = t / H;

    // hoisted clamped tap addresses + masks (plane-local)
    int taddr[9]; float tmask[9];
    #pragma unroll
    for (int dy = -1; dy <= 1; dy++) {
        #pragma unroll
        for (int dx = -1; dx <= 1; dx++) {
            int k = (dy + 1) * 3 + (dx + 1);
            int yy = y + dy, xx = x + dx;
            bool v = (yy >= 0) && (yy < H) && (xx >= 0) && (xx < W);
            int yc = min(max(yy, 0), H - 1), xc = min(max(xx, 0), W - 1);
            taddr[k] = yc * W + xc;
            tmask[k] = v ? 1.f : 0.f;
        }
    }

    float acc[24];
    #pragma unroll
    for (int o = 0; o < 24; o++) acc[o] = b_oa[o];

    const float* gch = guidance + (size_t)b * NUMCH * HW;
    for (int i = 0; i < NUMCH; i++) {
        float g[9];
        #pragma unroll
        for (int k = 0; k < 9; k++) g[k] = gch[taddr[k]] * tmask[k];
        #pragma unroll
        for (int k = 0; k < 9; k++) {
            const float* wrow = Wt + (i * 9 + k) * 24;   // uniform, contiguous
            #pragma unroll
            for (int o = 0; o < 24; o++) acc[o] = fmaf(g[k], wrow[o], acc[o]);
        }
        gch += HW;
    }

    float offy[9], offx[9];
    #pragma unroll
    for (int n = 0; n < 9; n++) {
        if (n < 4)       { offy[n] = acc[2 * n];     offx[n] = acc[2 * n + 1]; }
        else if (n == 4) { offy[n] = 0.f;            offx[n] = 0.f; }
        else             { offy[n] = acc[2 * n - 2]; offx[n] = acc[2 * n - 1]; }
    }

    size_t obase = (size_t)b * 18 * HW + (size_t)y * W + x;
    #pragma unroll
    for (int n = 0; n < 9; n++) {
        out_offset[obase + (size_t)(2 * n) * HW]     = offy[n];
        out_offset[obase + (size_t)(2 * n + 1) * HW] = offx[n];
    }

    float scale = aff_scale[0] + 1e-8f;
    const float* conf = confidence + (size_t)b * HW;
    float yf = (float)y, xf = (float)x;
    float aff[8];
    float s = 0.f;
    #pragma unroll
    for (int i = 0; i < 8; i++) {
        int n = (i < 4) ? i : i + 1;
        float a = tanh_fast(acc[16 + i]) / scale;
        float c = bilin(conf, yf + offy[n], xf + offx[n]);
        a *= c;
        aff[i] = a;
        s += fabsf(a);
    }
    float denom = fmaxf(s + 1e-4f, 1.0f);
    float inv = __fdividef(1.f, denom);
    float sum = 0.f;
    #pragma unroll
    for (int i = 0; i < 8; i++) { aff[i] *= inv; sum += aff[i]; }
    float aref = 1.f - sum;

    float a9[9];
    #pragma unroll
    for (int n = 0; n < 9; n++)
        a9[n] = (n < 4) ? aff[n] : ((n == 4) ? aref : aff[n - 1]);

    size_t abase = (size_t)b * 9 * HW + (size_t)y * W + x;
    #pragma unroll
    for (int n = 0; n < 9; n++)
        out_aff[abase + (size_t)n * HW] = a9[n];

    if (p_o03) {
        uint4 u;
        u.x = pk2(offy[0], offx[0]); u.y = pk2(offy[1], offx[1]);
        u.z = pk2(offy[2], offx[2]); u.w = pk2(offy[3], offx[3]);
        p_o03[idx] = u;
        u.x = pk2(offy[5], offx[5]); u.y = pk2(offy[6], offx[6]);
        u.z = pk2(offy[7], offx[7]); u.w = pk2(offy[8], offx[8]);
        p_o47[idx] = u;
        u.x = pk2(a9[0], a9[1]); u.y = pk2(a9[2], a9[3]);
        u.z = pk2(a9[5], a9[6]); u.w = pk2(a9[7], a9[8]);
        p_ap[idx] = u;
        p_a4[idx] = a9[4];
    }
}

// Tiled propagation: LDS halo tile, vec4 params, global fallback for |off|>=1.
__global__ __launch_bounds__(256) void prop_fast(
    const float* __restrict__ src, float* __restrict__ dst,
    const uint4* __restrict__ p_o03, const uint4* __restrict__ p_o47,
    const uint4* __restrict__ p_ap, const float* __restrict__ p_a4)
{
    __shared__ float tile[TR * TS];
    int blk = blockIdx.x;
    int bc = blk % NXB;
    int t2 = blk / NXB;
    int br = t2 % NYB;
    int b  = t2 / NYB;
    int xb = bc * XB, yb = br * YB;

    int lane = threadIdx.x & 63;
    int r0 = threadIdx.x >> 6;
    int y = yb + r0, x = xb + lane;
    int px = (b * H + y) * W + x;

    // issue param loads before staging (latency overlap)
    uint4 o03 = p_o03[px];
    uint4 o47 = p_o47[px];
    uint4 ap  = p_ap[px];
    float a4  = p_a4[px];

    const float* plane = src + (size_t)b * HW;
    for (int j = threadIdx.x; j < TR * TC; j += 256) {
        int rr = j / TC, cc = j % TC;
        int gy = yb - 2 + rr, gx = xb - 2 + cc;
        float v = 0.f;
        if ((unsigned)gy < (unsigned)H && (unsigned)gx < (unsigned)W)
            v = plane[gy * W + gx];
        tile[rr * TS + cc] = v;
    }
    __syncthreads();

    float yf = (float)y, xf = (float)x;
    float res = a4 * tile[(r0 + 2) * TS + (lane + 2)];

    const unsigned po[8] = {o03.x, o03.y, o03.z, o03.w, o47.x, o47.y, o47.z, o47.w};
    const unsigned pa[4] = {ap.x, ap.y, ap.z, ap.w};

    #pragma unroll
    for (int m = 0; m < 8; m++) {
        int n = (m < 4) ? m : m + 1;
        float dy = (float)(n / 3 - 1), dx = (float)(n % 3 - 1);
        float offy = uph_lo(po[m]);
        float offx = uph_hi(po[m]);
        unsigned aw = pa[m >> 1];
        float a = (m & 1) ? uph_hi(aw) : uph_lo(aw);
        float ys = yf + dy + offy;
        float xs = xf + dx + offx;
        float y0f = floorf(ys), x0f = floorf(xs);
        float wy = ys - y0f, wx = xs - x0f;
        int ty = (int)y0f - (yb - 2);
        int tx = (int)x0f - (xb - 2);
        float v00, v01, v10, v11;
        if ((unsigned)ty <= (unsigned)(TR - 2) && (unsigned)tx <= (unsigned)(TC - 2)) {
            const float* tp = &tile[ty * TS + tx];
            v00 = tp[0]; v01 = tp[1]; v10 = tp[TS]; v11 = tp[TS + 1];
        } else {  // ~never: |offset| >= 1
            float y0g = y0f, x0g = x0f;
            int y0 = (int)y0g, x0 = (int)x0g;
            int y1 = y0 + 1, x1 = x0 + 1;
            int yc0 = min(max(y0, 0), H - 1), yc1 = min(max(y1, 0), H - 1);
            int xc0 = min(max(x0, 0), W - 1), xc1 = min(max(x1, 0), W - 1);
            bool yv0 = (y0 >= 0) & (y0 < H), yv1 = (y1 >= 0) & (y1 < H);
            bool xv0 = (x0 >= 0) & (x0 < W), xv1 = (x1 >= 0) & (x1 < W);
            v00 = (yv0 && xv0) ? plane[yc0 * W + xc0] : 0.f;
            v01 = (yv0 && xv1) ? plane[yc0 * W + xc1] : 0.f;
            v10 = (yv1 && xv0) ? plane[yc1 * W + xc0] : 0.f;
            v11 = (yv1 && xv1) ? plane[yc1 * W + xc1] : 0.f;
        }
        float w1y = 1.f - wy, w1x = 1.f - wx;
        res = fmaf(a, w1y * (w1x * v00 + wx * v01) + wy * (w1x * v10 + wx * v11), res);
    }
    dst[px] = res;
}

// Fallback propagation (f32 params from d_out) if ws too small.
__global__ __launch_bounds__(256) void prop_slow(
    const float* __restrict__ src, float* __restrict__ dst,
    const float* __restrict__ out_offset, const float* __restrict__ out_aff)
{
    int idx = blockIdx.x * 256 + threadIdx.x;
    int x = idx % W;
    int t = idx / W;
    int y = t % H;
    int b = t / H;
    const float* plane = src + (size_t)b * HW;
    size_t obase = (size_t)b * 18 * HW + (size_t)y * W + x;
    size_t abase = (size_t)b * 9 * HW + (size_t)y * W + x;
    float r = 0.f;
    #pragma unroll
    for (int n = 0; n < 9; n++) {
        float offy = out_offset[obase + (size_t)(2 * n) * HW];
        float offx = out_offset[obase + (size_t)(2 * n + 1) * HW];
        float a    = out_aff[abase + (size_t)n * HW];
        float ys = (float)y + (float)(n / 3 - 1) + offy;
        float xs = (float)x + (float)(n % 3 - 1) + offx;
        r = fmaf(a, bilin(plane, ys, xs), r);
    }
    dst[(size_t)b * HW + (size_t)y * W + x] = r;
}

extern "C" void kernel_launch(void* const* d_in, const int* in_sizes, int n_in,
                              void* d_out, int out_size, void* d_ws, size_t ws_size,
                              hipStream_t stream) {
    const float* guidance   = (const float*)d_in[0];
    const float* confidence = (const float*)d_in[1];
    const float* feat_init  = (const float*)d_in[2];
    const float* W_oa       = (const float*)d_in[3];
    const float* b_oa       = (const float*)d_in[4];
    const float* aff_scale  = (const float*)d_in[5];

    float* out        = (float*)d_out;
    float* out_feat   = out;
    float* out_offset = out + (size_t)PIX;
    float* out_aff    = out + (size_t)PIX + (size_t)BN * 18 * HW;

    // ws layout: Wt(2048 f) | featA | featB | p_o03 | p_o47 | p_ap | p_a4
    float* ws_f = (float*)d_ws;
    float* Wt    = ws_f;
    float* featA = ws_f + 2048;
    float* featB = featA + (size_t)PIX;
    uint4* p_o03 = (uint4*)(featB + (size_t)PIX);
    uint4* p_o47 = p_o03 + (size_t)PIX;
    uint4* p_ap  = p_o47 + (size_t)PIX;
    float* p_a4  = (float*)(p_ap + (size_t)PIX);

    size_t need = 2048 * 4 + (size_t)PIX * (4 + 4 + 16 + 16 + 16 + 4);
    bool fast = (ws_size >= need);
    size_t need_slow = 2048 * 4 + (size_t)PIX * 4;
    bool have_wt = (ws_size >= need_slow);

    if (have_wt) transpose_w<<<7, 256, 0, stream>>>(W_oa, Wt);

    prep_kernel<<<PIX / 256, 256, 0, stream>>>(
        guidance, confidence, Wt, b_oa, aff_scale, out_offset, out_aff,
        fast ? p_o03 : nullptr, fast ? p_o47 : nullptr,
        fast ? p_ap : nullptr, fast ? p_a4 : nullptr);

    const float* src = feat_init;
    if (fast) {
        for (int k = 1; k <= PROP_TIME; k++) {
            float* dst = (k == PROP_TIME) ? out_feat : ((k & 1) ? featA : featB);
            prop_fast<<<BN * NYB * NXB, 256, 0, stream>>>(src, dst, p_o03, p_o47, p_ap, p_a4);
            src = dst;
        }
    } else {
        for (int k = 1; k <= PROP_TIME; k++) {
            float* dst = (k % 2 == 1) ? featA : out_feat;
            prop_slow<<<PIX / 256, 256, 0, stream>>>(src, dst, out_offset, out_aff);
            src = dst;
        }
    }
}